// Round 3
// baseline (1706.099 us; speedup 1.0000x reference)
//
#include <hip/hip_runtime.h>

#define EXPERTS 8
#define ODIM 4096
#define IDIM 1024
#define BATCH 16
#define SEQ 2048

typedef __attribute__((ext_vector_type(8))) short bf16x8;
typedef __attribute__((ext_vector_type(4))) float f32x4;

__device__ __forceinline__ unsigned short to_bf16(float f) {
    union { float f; unsigned u; } v; v.f = f;
    return (unsigned short)((v.u + 0x7FFFu + ((v.u >> 16) & 1u)) >> 16);
}

__device__ __forceinline__ void gload_lds16(const unsigned short* g, unsigned short* l) {
    __builtin_amdgcn_global_load_lds(
        (const __attribute__((address_space(1))) void*)g,
        (__attribute__((address_space(3))) void*)l,
        16, 0, 0);
}

// ---------------- pass 1: fp32 -> bf16 for x and all expert weights ----------------
__global__ __launch_bounds__(256)
void convert_bf16_kernel(const float* __restrict__ x, const float* __restrict__ w,
                         unsigned short* __restrict__ xb, unsigned short* __restrict__ wb) {
    const size_t NX = (size_t)BATCH * SEQ * IDIM;
    const size_t NT = NX + (size_t)EXPERTS * ODIM * IDIM;
    const size_t stride = (size_t)gridDim.x * blockDim.x * 8;
    for (size_t i = ((size_t)blockIdx.x * blockDim.x + threadIdx.x) * 8; i < NT; i += stride) {
        const float* src; unsigned short* dst; size_t off;
        if (i < NX) { src = x; dst = xb; off = i; }
        else        { src = w; dst = wb; off = i - NX; }
        const f32x4 v0 = *(const f32x4*)(src + off);
        const f32x4 v1 = *(const f32x4*)(src + off + 4);
        union { unsigned short s[8]; bf16x8 v; } o;
        o.s[0] = to_bf16(v0.x); o.s[1] = to_bf16(v0.y);
        o.s[2] = to_bf16(v0.z); o.s[3] = to_bf16(v0.w);
        o.s[4] = to_bf16(v1.x); o.s[5] = to_bf16(v1.y);
        o.s[6] = to_bf16(v1.z); o.s[7] = to_bf16(v1.w);
        *(bf16x8*)(dst + off) = o.v;
    }
}

// =================== pass 2a: 256x256 8-phase GEMM (T1+T2+T3+T4+T5) ===================
// 8 waves (2M x 4N), BK=64, 128 KiB dyn LDS: A[2buf][2half][128x64] then B same.
// wave wr owns m-frags: half mh rows mh*128 + wr*64 + mf*16 (mf 0..3)
// wave wc owns n-frags: half nh cols nh*128 + wc*32 + nf*16 (nf 0..1)
#define NKT 16   // K tiles of 64

#define BAR() __builtin_amdgcn_s_barrier()
#define PRIO1 __builtin_amdgcn_s_setprio(1)
#define PRIO0 __builtin_amdgcn_s_setprio(0)
#define WAIT_LGKM0 do { asm volatile("s_waitcnt lgkmcnt(0)" ::: "memory"); \
                        __builtin_amdgcn_sched_barrier(0); } while (0)
#define WAIT_VM(n) do { asm volatile("s_waitcnt vmcnt(" #n ")" ::: "memory"); \
                        __builtin_amdgcn_sched_barrier(0); } while (0)

// stage one half-tile (2 x global_load_lds_dwordx4 per thread)
#define STG_A(buf, h, kt) do { \
    gload_lds16(aG + (size_t)(h) * 128 * IDIM + (kt) * 64,       ldsA + (buf) * 16384 + (h) * 8192 + w2 * 512); \
    gload_lds16(aG + (size_t)((h) * 128 + 8) * IDIM + (kt) * 64, ldsA + (buf) * 16384 + (h) * 8192 + (w2 + 1) * 512); \
} while (0)
#define STG_B(buf, h, kt) do { \
    gload_lds16(bG + (size_t)(h) * 128 * IDIM + (kt) * 64,       ldsB + (buf) * 16384 + (h) * 8192 + w2 * 512); \
    gload_lds16(bG + (size_t)((h) * 128 + 8) * IDIM + (kt) * 64, ldsB + (buf) * 16384 + (h) * 8192 + (w2 + 1) * 512); \
} while (0)

#define LDA_Q(buf, mh) do { \
    const char* _p = ldc + (buf) * 32768 + (mh) * 16384 + aRd; \
    af[0][0] = *(const bf16x8*)(_p);        af[0][1] = *(const bf16x8*)(_p + 64); \
    af[1][0] = *(const bf16x8*)(_p + 2048); af[1][1] = *(const bf16x8*)(_p + 2112); \
    af[2][0] = *(const bf16x8*)(_p + 4096); af[2][1] = *(const bf16x8*)(_p + 4160); \
    af[3][0] = *(const bf16x8*)(_p + 6144); af[3][1] = *(const bf16x8*)(_p + 6208); \
} while (0)
#define LDB_Q(buf, nh) do { \
    const char* _p = ldc + (buf) * 32768 + (nh) * 16384 + bRd; \
    bfr[0][0] = *(const bf16x8*)(_p);        bfr[0][1] = *(const bf16x8*)(_p + 64); \
    bfr[1][0] = *(const bf16x8*)(_p + 2048); bfr[1][1] = *(const bf16x8*)(_p + 2112); \
} while (0)

#define MFMA_Q(mh, nh) do { \
    _Pragma("unroll") \
    for (int mf = 0; mf < 4; ++mf) { \
        acc[(mh)*4+mf][(nh)*2+0] = __builtin_amdgcn_mfma_f32_16x16x32_bf16(af[mf][0], bfr[0][0], acc[(mh)*4+mf][(nh)*2+0], 0, 0, 0); \
        acc[(mh)*4+mf][(nh)*2+0] = __builtin_amdgcn_mfma_f32_16x16x32_bf16(af[mf][1], bfr[0][1], acc[(mh)*4+mf][(nh)*2+0], 0, 0, 0); \
        acc[(mh)*4+mf][(nh)*2+1] = __builtin_amdgcn_mfma_f32_16x16x32_bf16(af[mf][0], bfr[1][0], acc[(mh)*4+mf][(nh)*2+1], 0, 0, 0); \
        acc[(mh)*4+mf][(nh)*2+1] = __builtin_amdgcn_mfma_f32_16x16x32_bf16(af[mf][1], bfr[1][1], acc[(mh)*4+mf][(nh)*2+1], 0, 0, 0); \
    } \
} while (0)

__global__ __launch_bounds__(512, 2)
void moe_gemm_8ph(const unsigned short* __restrict__ xb,
                  const unsigned short* __restrict__ wb,
                  const float* __restrict__ probs,
                  const float* __restrict__ bias,
                  float* __restrict__ out) {
    extern __shared__ char lds[];
    __shared__ int s_e;

    // bijective XCD swizzle: 2048 blocks, 8 XCDs -> 256 contiguous wgs per XCD
    const int orig = blockIdx.x;
    const int wg = (orig & 7) * 256 + (orig >> 3);
    const int tn = wg & 15;          // 16 n-tiles
    const int tm = (wg >> 4) & 7;    // 8 m-tiles
    const int b  = wg >> 7;          // 16 batches

    const int tid = threadIdx.x;
    if (tid == 0) {
        float best = probs[b * EXPERTS];
        int bi = 0;
        #pragma unroll
        for (int e2 = 1; e2 < EXPERTS; ++e2) {
            float p = probs[b * EXPERTS + e2];
            if (p > best) { best = p; bi = e2; }
        }
        s_e = bi;
    }
    __syncthreads();
    const int e = s_e;

    const int m0 = tm * 256, n0 = tn * 256;
    const int lane = tid & 63;
    const int w  = tid >> 6;   // 0..7
    const int wr = w >> 2;     // 0..1
    const int wc = w & 3;      // 0..3
    const int w2 = w * 2;
    const int frow = lane & 15;
    const int fkb  = (lane >> 4) << 4;        // k byte offset (0/16/32/48)
    const int sw   = (frow & 4) << 3;         // st_16x32 swizzle term (byte bit5 ^= row bit2)
    const int fko  = fkb ^ sw;                // XOR, not add! (rule #21: same involution both sides)

    // staging source map (inverse-swizzled global source: chunk ^= row-bit2 of staged row)
    const int srow_l = lane >> 3;
    const int scol_l = ((lane & 7) ^ ((lane >> 5) << 1)) * 8;
    const unsigned short* aG = xb + ((size_t)b * SEQ + m0 + w2 * 8 + srow_l) * IDIM + scol_l;
    const unsigned short* bG = wb + ((size_t)e * ODIM + n0 + w2 * 8 + srow_l) * IDIM + scol_l;
    unsigned short* ldsA = (unsigned short*)lds;            // bytes [0, 65536)
    unsigned short* ldsB = (unsigned short*)(lds + 65536);  // bytes [65536, 131072)
    const char* ldc = (const char*)lds;
    const int aRd = (wr * 64 + frow) * 128 + fko;           // within A half
    const int bRd = 65536 + (wc * 32 + frow) * 128 + fko;   // abs, within B half

    f32x4 acc[8][4];
    #pragma unroll
    for (int i = 0; i < 8; ++i)
        #pragma unroll
        for (int j = 0; j < 4; ++j)
            acc[i][j] = (f32x4){0.f, 0.f, 0.f, 0.f};
    bf16x8 af[4][2], bfr[2][2];

    // prologue: tile0 full (buf0), tile1 B0+A1 (buf1); allow newest 4 loads in flight
    STG_A(0, 0, 0); STG_A(0, 1, 0); STG_B(0, 0, 0); STG_B(0, 1, 0);
    STG_B(1, 0, 1); STG_A(1, 1, 1);
    WAIT_VM(4);
    BAR();

    #pragma unroll 1
    for (int i = 0; i < 8; ++i) {
        const int y = 2 * i + 1, x2 = 2 * i + 2, y2 = 2 * i + 3;
        const bool s2 = (x2 < NKT);
        // P1: X=(buf0) Q(0,0) | stage Y.B1
        LDA_Q(0, 0); LDB_Q(0, 0); STG_B(1, 1, y);
        BAR(); WAIT_LGKM0; PRIO1; MFMA_Q(0, 0); PRIO0; BAR();
        // P2: Q(1,0) | stage Y.A0
        LDA_Q(0, 1); STG_A(1, 0, y);
        BAR(); WAIT_LGKM0; PRIO1; MFMA_Q(1, 0); PRIO0; BAR();
        // P3: Q(1,1) | stage X'.B0
        LDB_Q(0, 1); if (s2) STG_B(0, 0, x2);
        BAR(); WAIT_LGKM0; PRIO1; MFMA_Q(1, 1); PRIO0; BAR();
        // P4: Q(0,1) | stage X'.A1 | counted vmcnt (tail drains)
        LDA_Q(0, 0); if (s2) STG_A(0, 1, x2);
        BAR(); WAIT_LGKM0; PRIO1; MFMA_Q(0, 1); PRIO0;
        if (s2) { WAIT_VM(4); } else { WAIT_VM(0); }
        BAR();
        // P5: Y=(buf1) Q(0,0) | stage X'.B1
        LDA_Q(1, 0); LDB_Q(1, 0); if (s2) STG_B(0, 1, x2);
        BAR(); WAIT_LGKM0; PRIO1; MFMA_Q(0, 0); PRIO0; BAR();
        // P6: Q(1,0) | stage X'.A0
        LDA_Q(1, 1); if (s2) STG_A(0, 0, x2);
        BAR(); WAIT_LGKM0; PRIO1; MFMA_Q(1, 0); PRIO0; BAR();
        // P7: Q(1,1) | stage Y'.B0
        LDB_Q(1, 1); if (s2) STG_B(1, 0, y2);
        BAR(); WAIT_LGKM0; PRIO1; MFMA_Q(1, 1); PRIO0; BAR();
        // P8: Q(0,1) | stage Y'.A1 | counted vmcnt
        LDA_Q(1, 0); if (s2) STG_A(1, 1, y2);
        BAR(); WAIT_LGKM0; PRIO1; MFMA_Q(0, 1); PRIO0;
        WAIT_VM(4);
        BAR();
    }

    // epilogue: + bias, fp32 store. C/D: col=lane&15, row=(lane>>4)*4+reg [m89]
    const float* bias_e = bias + (size_t)e * ODIM;
    const int rbase = (lane >> 4) * 4;
    #pragma unroll
    for (int nfg = 0; nfg < 4; ++nfg) {
        const int col = n0 + (nfg >> 1) * 128 + wc * 32 + (nfg & 1) * 16 + frow;
        const float bv = bias_e[col];
        #pragma unroll
        for (int mfg = 0; mfg < 8; ++mfg) {
            const int row = m0 + (mfg >> 2) * 128 + wr * 64 + (mfg & 3) * 16 + rbase;
            float* op = out + ((size_t)b * SEQ + row) * ODIM + col;
            #pragma unroll
            for (int r = 0; r < 4; ++r)
                op[(size_t)r * ODIM] = acc[mfg][nfg][r] + bv;
        }
    }
}

// =================== pass 2b fallback: round-1 128x128 m97-structure kernel ===================
__global__ __launch_bounds__(256)
void moe_gemm_bf16(const unsigned short* __restrict__ xb,
                   const unsigned short* __restrict__ wb,
                   const float* __restrict__ probs,
                   const float* __restrict__ bias,
                   float* __restrict__ out) {
    __shared__ unsigned short As[128 * 32];
    __shared__ unsigned short Bs[128 * 32];
    __shared__ int s_e;

    const int tn  = blockIdx.x;
    const int tm  = blockIdx.y;
    const int b   = blockIdx.z;
    const int tid = threadIdx.x;

    if (tid == 0) {
        float best = probs[b * EXPERTS];
        int bi = 0;
        #pragma unroll
        for (int e2 = 1; e2 < EXPERTS; ++e2) {
            float p = probs[b * EXPERTS + e2];
            if (p > best) { best = p; bi = e2; }
        }
        s_e = bi;
    }
    __syncthreads();
    const int e = s_e;

    const int m0 = tm * 128;
    const int n0 = tn * 128;
    const int lane = tid & 63;
    const int wave = tid >> 6;

    const int srow = wave * 16 + (lane >> 2);
    const int scol = (lane & 3) * 8;
    const unsigned short* ag = xb + ((size_t)b * SEQ + m0 + srow) * IDIM + scol;
    const unsigned short* bg = wb + ((size_t)e * ODIM + n0 + srow) * IDIM + scol;
    unsigned short* lA = As + wave * 512;
    unsigned short* lB = Bs + wave * 512;

    const int wm = (wave & 1) * 64;
    const int wn = (wave >> 1) * 64;
    const int frow = lane & 15;
    const int fk   = (lane >> 4) * 8;

    f32x4 acc[4][4];
    #pragma unroll
    for (int i = 0; i < 4; ++i)
        #pragma unroll
        for (int j = 0; j < 4; ++j)
            acc[i][j] = (f32x4){0.f, 0.f, 0.f, 0.f};

    for (int k0 = 0; k0 < IDIM; k0 += 32) {
        gload_lds16(ag + k0,                      lA);
        gload_lds16(ag + k0 + (size_t)64 * IDIM,  lA + 2048);
        gload_lds16(bg + k0,                      lB);
        gload_lds16(bg + k0 + (size_t)64 * IDIM,  lB + 2048);
        __syncthreads();

        bf16x8 a_frag[4], b_frag[4];
        #pragma unroll
        for (int i = 0; i < 4; ++i)
            a_frag[i] = *(const bf16x8*)&As[(wm + i * 16 + frow) * 32 + fk];
        #pragma unroll
        for (int j = 0; j < 4; ++j)
            b_frag[j] = *(const bf16x8*)&Bs[(wn + j * 16 + frow) * 32 + fk];

        #pragma unroll
        for (int i = 0; i < 4; ++i)
            #pragma unroll
            for (int j = 0; j < 4; ++j)
                acc[i][j] = __builtin_amdgcn_mfma_f32_16x16x32_bf16(
                    a_frag[i], b_frag[j], acc[i][j], 0, 0, 0);
        __syncthreads();
    }

    const float* bias_e = bias + (size_t)e * ODIM;
    const int rbase = (lane >> 4) * 4;
    #pragma unroll
    for (int j = 0; j < 4; ++j) {
        const int n = n0 + wn + j * 16 + frow;
        const float bv = bias_e[n];
        #pragma unroll
        for (int i = 0; i < 4; ++i) {
            const int mb = m0 + wm + i * 16 + rbase;
            float* op = out + ((size_t)b * SEQ + mb) * ODIM + n;
            #pragma unroll
            for (int r = 0; r < 4; ++r)
                op[(size_t)r * ODIM] = acc[i][j][r] + bv;
        }
    }
}

// =================== fp32 fallback (no workspace) ===================
__global__ __launch_bounds__(256)
void moe_gemm_fallback(const float* __restrict__ x,
                       const float* __restrict__ probs,
                       const float* __restrict__ w,
                       const float* __restrict__ bias,
                       float* __restrict__ out) {
    __shared__ unsigned short As[128 * 40];
    __shared__ unsigned short Bs[128 * 40];
    __shared__ int s_e;

    const int tn  = blockIdx.x;
    const int tm  = blockIdx.y;
    const int b   = blockIdx.z;
    const int tid = threadIdx.x;

    if (tid == 0) {
        float best = probs[b * EXPERTS];
        int bi = 0;
        #pragma unroll
        for (int e2 = 1; e2 < EXPERTS; ++e2) {
            float p = probs[b * EXPERTS + e2];
            if (p > best) { best = p; bi = e2; }
        }
        s_e = bi;
    }
    __syncthreads();
    const int e = s_e;

    const int m0 = tm * 128;
    const int n0 = tn * 128;
    const int srow = tid >> 3;
    const int scol = (tid & 7) * 4;

    const float* ag = x + ((size_t)b * SEQ + m0 + srow) * IDIM + scol;
    const float* bg = w + ((size_t)e * ODIM + n0 + srow) * IDIM + scol;

    const int lane = tid & 63;
    const int wave = tid >> 6;
    const int wm = (wave & 1) * 64;
    const int wn = (wave >> 1) * 64;
    const int frow = lane & 15;
    const int fk   = (lane >> 4) * 8;

    f32x4 acc[4][4];
    #pragma unroll
    for (int i = 0; i < 4; ++i)
        #pragma unroll
        for (int j = 0; j < 4; ++j)
            acc[i][j] = (f32x4){0.f, 0.f, 0.f, 0.f};

    for (int k0 = 0; k0 < IDIM; k0 += 32) {
        #pragma unroll
        for (int p = 0; p < 4; ++p) {
            const f32x4 av = *(const f32x4*)(ag + (size_t)p * 32 * IDIM);
            const f32x4 bv = *(const f32x4*)(bg + (size_t)p * 32 * IDIM);
            const int r = srow + p * 32;
            union { unsigned short s[4]; unsigned long long u; } pa, pb;
            pa.s[0] = to_bf16(av.x); pa.s[1] = to_bf16(av.y);
            pa.s[2] = to_bf16(av.z); pa.s[3] = to_bf16(av.w);
            pb.s[0] = to_bf16(bv.x); pb.s[1] = to_bf16(bv.y);
            pb.s[2] = to_bf16(bv.z); pb.s[3] = to_bf16(bv.w);
            *(unsigned long long*)&As[r * 40 + scol] = pa.u;
            *(unsigned long long*)&Bs[r * 40 + scol] = pb.u;
        }
        __syncthreads();

        bf16x8 a_frag[4], b_frag[4];
        #pragma unroll
        for (int i = 0; i < 4; ++i)
            a_frag[i] = *(const bf16x8*)&As[(wm + i * 16 + frow) * 40 + fk];
        #pragma unroll
        for (int j = 0; j < 4; ++j)
            b_frag[j] = *(const bf16x8*)&Bs[(wn + j * 16 + frow) * 40 + fk];

        #pragma unroll
        for (int i = 0; i < 4; ++i)
            #pragma unroll
            for (int j = 0; j < 4; ++j)
                acc[i][j] = __builtin_amdgcn_mfma_f32_16x16x32_bf16(
                    a_frag[i], b_frag[j], acc[i][j], 0, 0, 0);
        __syncthreads();

        ag += 32;
        bg += 32;
    }

    const float* bias_e = bias + (size_t)e * ODIM;
    const int rbase = (lane >> 4) * 4;
    #pragma unroll
    for (int j = 0; j < 4; ++j) {
        const int n = n0 + wn + j * 16 + frow;
        const float bv = bias_e[n];
        #pragma unroll
        for (int i = 0; i < 4; ++i) {
            const int mb = m0 + wm + i * 16 + rbase;
            float* op = out + ((size_t)b * SEQ + mb) * ODIM + n;
            #pragma unroll
            for (int r = 0; r < 4; ++r)
                op[(size_t)r * ODIM] = acc[i][j][r] + bv;
        }
    }
}

__global__ void moe_idx_kernel(const float* __restrict__ probs,
                               float* __restrict__ out_idx) {
    const int b = threadIdx.x;
    if (b < BATCH) {
        float best = probs[b * EXPERTS];
        int bi = 0;
        #pragma unroll
        for (int e2 = 1; e2 < EXPERTS; ++e2) {
            float p = probs[b * EXPERTS + e2];
            if (p > best) { best = p; bi = e2; }
        }
        out_idx[b] = (float)bi;
    }
}

extern "C" void kernel_launch(void* const* d_in, const int* in_sizes, int n_in,
                              void* d_out, int out_size, void* d_ws, size_t ws_size,
                              hipStream_t stream) {
    const float* x     = (const float*)d_in[0];
    const float* probs = (const float*)d_in[1];
    const float* w     = (const float*)d_in[2];
    const float* bias  = (const float*)d_in[3];
    float* out = (float*)d_out;

    const size_t nxb = (size_t)BATCH * SEQ * IDIM;
    const size_t nwb = (size_t)EXPERTS * ODIM * IDIM;
    const size_t need = (nxb + nwb) * sizeof(unsigned short);  // 128 MiB

    // one-time opt-in for 128 KiB dynamic LDS (not a stream op; graph-capture safe)
    static int can8ph = 0;
    if (can8ph == 0) {
        hipError_t err = hipFuncSetAttribute(
            reinterpret_cast<const void*>(moe_gemm_8ph),
            hipFuncAttributeMaxDynamicSharedMemorySize, 131072);
        can8ph = (err == hipSuccess) ? 1 : -1;
    }

    if (ws_size >= need) {
        unsigned short* xbuf = (unsigned short*)d_ws;
        unsigned short* wbuf = xbuf + nxb;
        convert_bf16_kernel<<<2048, 256, 0, stream>>>(x, w, xbuf, wbuf);
        if (can8ph == 1) {
            moe_gemm_8ph<<<dim3(2048), 512, 131072, stream>>>(xbuf, wbuf, probs, bias, out);
        } else {
            dim3 grid(ODIM / 128, SEQ / 128, BATCH);
            moe_gemm_bf16<<<grid, 256, 0, stream>>>(xbuf, wbuf, probs, bias, out);
        }
    } else {
        dim3 grid(ODIM / 128, SEQ / 128, BATCH);
        moe_gemm_fallback<<<grid, 256, 0, stream>>>(x, probs, w, bias, out);
    }
    moe_idx_kernel<<<1, 64, 0, stream>>>(probs, out + (size_t)BATCH * SEQ * ODIM);
}